// Round 6
// baseline (497.983 us; speedup 1.0000x reference)
//
#include <hip/hip_runtime.h>
#include <stdint.h>

#define B_ 128
#define T_ 1000
#define H_ 512
#define PH 8          // steps per phase
#define NPH 125       // compute phases (steps = NPH*PH = 1000)
#define SLOTS 16      // ring slots (2 phases worth)

typedef float vfloat4 __attribute__((ext_vector_type(4)));

// DPP-based add of a lane-shifted copy. row_shr:N = 0x110|N, row_bcast:15/31 = 0x142/0x143.
template <int CTRL>
__device__ __forceinline__ float dpp_add(float x) {
    int moved = __builtin_amdgcn_update_dpp(0, __float_as_int(x), CTRL, 0xf, 0xf, true);
    return x + __int_as_float(moved);
}

// Wave64 sum of 3 values simultaneously (3-way ILP covers DPP latency). Valid in lane 63.
__device__ __forceinline__ void wave_reduce3(float& p0, float& p1, float& p2) {
    p0 = dpp_add<0x111>(p0); p1 = dpp_add<0x111>(p1); p2 = dpp_add<0x111>(p2);
    p0 = dpp_add<0x112>(p0); p1 = dpp_add<0x112>(p1); p2 = dpp_add<0x112>(p2);
    p0 = dpp_add<0x114>(p0); p1 = dpp_add<0x114>(p1); p2 = dpp_add<0x114>(p2);
    p0 = dpp_add<0x118>(p0); p1 = dpp_add<0x118>(p1); p2 = dpp_add<0x118>(p2);
    p0 = dpp_add<0x142>(p0); p1 = dpp_add<0x142>(p1); p2 = dpp_add<0x142>(p2);
    p0 = dpp_add<0x143>(p0); p1 = dpp_add<0x143>(p1); p2 = dpp_add<0x143>(p2);
}

// tanh(x) = 1 - 2/(e^{2x}+1) via hardware exp2 + rcp.
__device__ __forceinline__ float fast_tanh(float x) {
    float E = __builtin_amdgcn_exp2f(x * 2.885390081777927f);
    float r = __builtin_amdgcn_rcpf(E + 1.0f);
    return __builtin_fmaf(-2.0f, r, 1.0f);
}

// LDS-visibility barrier that does NOT drain vmcnt: DMAs/stores stay in flight.
__device__ __forceinline__ void barrier_lds() {
    asm volatile("s_waitcnt lgkmcnt(0)" ::: "memory");
    __builtin_amdgcn_s_barrier();
}

// Async global->LDS, 16B per lane. LDS dest = wave-uniform base + lane*16.
__device__ __forceinline__ void gl_lds16(const float* g, float* l) {
    __builtin_amdgcn_global_load_lds(
        (const __attribute__((address_space(1))) uint32_t*)g,
        (__attribute__((address_space(3))) uint32_t*)l, 16, 0, 0);
}

__global__ __launch_bounds__(192, 1) void lowrank_rnn_kernel(
    const float* __restrict__ input,   // (B,T,3)
    const float* __restrict__ noise,   // (B,T,H)
    const float* __restrict__ wi,      // (3,H)
    const float* __restrict__ si,      // (3,)
    const float* __restrict__ m,       // (H,2)
    const float* __restrict__ n,       // (H,2)
    const float* __restrict__ wo,      // (H,1)
    const float* __restrict__ so,      // (1,)
    const float* __restrict__ h0,      // (H,)
    float* __restrict__ out)           // [output (B,T,1) | traj (B,T+1,H)]
{
    const int b    = blockIdx.x;
    const int tid  = threadIdx.x;
    const int wid  = tid >> 6;     // 0=compute, 1=loader, 2=writer
    const int lane = tid & 63;
    const int j0   = lane * 8;

    __shared__ __align__(16) float zring[SLOTS][H_];  // 32 KB: raw noise rows (loader-private)
    __shared__ __align__(16) float uring[SLOTS][H_];  // 32 KB: u_t = 0.05 z + x·wS
    __shared__ __align__(16) float hring[SLOTS][H_];  // 32 KB: h rows for writer
    __shared__ float xs[T_ * 3];                      // 12 KB: input sequence
    __shared__ float os[T_ + 1];                      //  4 KB: per-step outputs

    float* trajBase = out + (size_t)B_ * T_ + (size_t)b * (T_ + 1) * H_;
    const float* zbase = noise + (size_t)b * T_ * H_;

    if (wid == 0) {
        // ================= COMPUTE wave: pure serial chain, zero VMEM =================
        float h[8], n0[8], n1[8], m0S[8], m1S[8], wof[8];
        {
            const float so0 = so[0];
            const float* nb = n + 2 * j0;
            const float* mb = m + 2 * j0;
            #pragma unroll
            for (int q = 0; q < 4; ++q) {
                vfloat4 vn = *(const vfloat4*)(nb + 4 * q);
                n0[2*q] = vn.x; n1[2*q] = vn.y; n0[2*q+1] = vn.z; n1[2*q+1] = vn.w;
                vfloat4 vm = *(const vfloat4*)(mb + 4 * q);
                m0S[2*q] = 0.2f * vm.x;   m1S[2*q] = 0.2f * vm.y;
                m0S[2*q+1] = 0.2f * vm.z; m1S[2*q+1] = 0.2f * vm.w;
            }
            #pragma unroll
            for (int q = 0; q < 2; ++q) {
                vfloat4 vw = *(const vfloat4*)(wo + j0 + 4 * q);
                wof[4*q] = vw.x * so0; wof[4*q+1] = vw.y * so0;
                wof[4*q+2] = vw.z * so0; wof[4*q+3] = vw.w * so0;
                vfloat4 vh = *(const vfloat4*)(h0 + j0 + 4 * q);
                h[4*q] = vh.x; h[4*q+1] = vh.y; h[4*q+2] = vh.z; h[4*q+3] = vh.w;
            }
        }
        barrier_lds();   // A
        barrier_lds();   // B: u for phase 0 ready

        for (int ph = 0; ph <= NPH; ++ph) {
            if (ph < NPH) {
                const int t0 = ph * PH;
                #pragma unroll
                for (int s = 0; s < PH; ++s) {
                    const int t = t0 + s;
                    // u for this step (lgkm wait lands just before 'base' use below)
                    char* ub = (char*)&uring[t & (SLOTS-1)][0] + lane * 32;
                    vfloat4 ulo = *(vfloat4*)ub;
                    vfloat4 uhi = *(vfloat4*)(ub + 16);

                    float r[8];
                    #pragma unroll
                    for (int k = 0; k < 8; ++k) r[k] = fast_tanh(h[k]);

                    float p0 = r[0] * n0[0], p1 = r[0] * n1[0], p2 = r[0] * wof[0];
                    #pragma unroll
                    for (int k = 1; k < 8; ++k) {
                        p0 = __builtin_fmaf(r[k], n0[k], p0);
                        p1 = __builtin_fmaf(r[k], n1[k], p1);
                        p2 = __builtin_fmaf(r[k], wof[k], p2);
                    }
                    wave_reduce3(p0, p1, p2);

                    float uu[8] = {ulo.x, ulo.y, ulo.z, ulo.w, uhi.x, uhi.y, uhi.z, uhi.w};
                    float base[8];
                    #pragma unroll
                    for (int k = 0; k < 8; ++k)
                        base[k] = __builtin_fmaf(h[k], 0.8f, uu[k]);

                    float a0 = __int_as_float(__builtin_amdgcn_readlane(__float_as_int(p0), 63));
                    float a1 = __int_as_float(__builtin_amdgcn_readlane(__float_as_int(p1), 63));
                    if (lane == 63) os[t] = p2;   // out[t-1] = tanh(h_t)·wo_full

                    #pragma unroll
                    for (int k = 0; k < 8; ++k)
                        h[k] = __builtin_fmaf(a0, m0S[k], __builtin_fmaf(a1, m1S[k], base[k]));

                    char* hb = (char*)&hring[(t + 1) & (SLOTS-1)][0] + lane * 32;
                    vfloat4 hlo = {h[0], h[1], h[2], h[3]};
                    vfloat4 hhi = {h[4], h[5], h[6], h[7]};
                    *(vfloat4*)hb        = hlo;
                    *(vfloat4*)(hb + 16) = hhi;
                }
            } else {
                // final output: out[T-1] = tanh(h_T)·wo_full
                float r[8];
                #pragma unroll
                for (int k = 0; k < 8; ++k) r[k] = fast_tanh(h[k]);
                float p2 = r[0] * wof[0];
                #pragma unroll
                for (int k = 1; k < 8; ++k) p2 = __builtin_fmaf(r[k], wof[k], p2);
                p2 = dpp_add<0x111>(p2); p2 = dpp_add<0x112>(p2);
                p2 = dpp_add<0x114>(p2); p2 = dpp_add<0x118>(p2);
                p2 = dpp_add<0x142>(p2); p2 = dpp_add<0x143>(p2);
                if (lane == 63) os[T_] = p2;
            }
            barrier_lds();
        }
    } else if (wid == 1) {
        // ================= LOADER wave: DMA noise + precompute u =================
        float wS0[8], wS1[8], wS2[8];
        {
            #pragma unroll
            for (int i = 0; i < 3; ++i) {
                float s = 0.2f * si[i];
                float* dst = (i == 0) ? wS0 : (i == 1) ? wS1 : wS2;
                #pragma unroll
                for (int q = 0; q < 2; ++q) {
                    vfloat4 vw = *(const vfloat4*)(wi + i * H_ + j0 + 4 * q);
                    dst[4*q] = vw.x * s; dst[4*q+1] = vw.y * s;
                    dst[4*q+2] = vw.z * s; dst[4*q+3] = vw.w * s;
                }
            }
        }
        // Fill: DMA rows 0..15 (2 ops per row; 32 outstanding max).
        for (int s = 0; s < SLOTS; ++s) {
            const float* g = zbase + (size_t)s * H_ + j0;
            gl_lds16(g,     &zring[s][0]);
            gl_lds16(g + 4, &zring[s][256]);
        }

        // produce u for step s: wait for row-s DMA, read z, re-issue DMA, compute u.
        auto produce = [&](int s) {
            // 15 younger row-pairs (30 ops) in flight => oldest (row s) retired.
            asm volatile("s_waitcnt vmcnt(30)" ::: "memory");
            char* zb = (char*)&zring[s & (SLOTS-1)][0];
            vfloat4 zl = *(vfloat4*)(zb + lane * 16);          // z[j0..j0+4)
            vfloat4 zh = *(vfloat4*)(zb + 1024 + lane * 16);   // z[j0+4..j0+8)
            // Re-issue DMA for row s+16 into this slot (clamped: keeps count uniform).
            int srow = s + SLOTS; if (srow > T_ - 1) srow = T_ - 1;
            const float* g = zbase + (size_t)srow * H_ + j0;
            gl_lds16(g,     &zring[s & (SLOTS-1)][0]);
            gl_lds16(g + 4, &zring[s & (SLOTS-1)][256]);

            float x0 = xs[3*s], x1 = xs[3*s+1], x2 = xs[3*s+2];
            float zz[8] = {zl.x, zl.y, zl.z, zl.w, zh.x, zh.y, zh.z, zh.w};
            float u[8];
            #pragma unroll
            for (int k = 0; k < 8; ++k) {
                float xw = __builtin_fmaf(x0, wS0[k],
                           __builtin_fmaf(x1, wS1[k], x2 * wS2[k]));
                u[k] = __builtin_fmaf(zz[k], 0.05f, xw);
            }
            char* ub = (char*)&uring[s & (SLOTS-1)][0] + lane * 32;
            vfloat4 ulo = {u[0], u[1], u[2], u[3]};
            vfloat4 uhi = {u[4], u[5], u[6], u[7]};
            *(vfloat4*)ub        = ulo;
            *(vfloat4*)(ub + 16) = uhi;
        };

        barrier_lds();   // A: xs (written by writer) now visible
        for (int s = 0; s < PH; ++s) produce(s);   // u for phase 0
        barrier_lds();   // B

        for (int ph = 0; ph <= NPH; ++ph) {
            if (ph <= NPH - 2) {
                const int s0 = (ph + 1) * PH;
                for (int s = s0; s < s0 + PH; ++s) produce(s);
            }
            barrier_lds();
        }
    } else {
        // ================= WRITER wave: stage x, store trajectory =================
        // Stage x into LDS (loader reads it; keeps loader's vmcnt stream pure-DMA).
        for (int idx = lane; idx < T_ * 3; idx += 64)
            xs[idx] = input[(size_t)b * T_ * 3 + idx];
        {   // trajectories[:,0,:] = h0
            vfloat4 a = *(const vfloat4*)(h0 + lane * 4);
            vfloat4 c = *(const vfloat4*)(h0 + 256 + lane * 4);
            *(vfloat4*)(trajBase + lane * 4)       = a;
            *(vfloat4*)(trajBase + 256 + lane * 4) = c;
        }
        barrier_lds();   // A
        barrier_lds();   // B

        for (int ph = 0; ph <= NPH; ++ph) {
            if (ph >= 1) {
                const int t0 = (ph - 1) * PH;
                #pragma unroll
                for (int s = 0; s < PH; ++s) {
                    const int row = t0 + s + 1;          // h_{row}
                    char* hb = (char*)&hring[row & (SLOTS-1)][0];
                    vfloat4 v = *(vfloat4*)(hb + lane * 16);
                    vfloat4 w = *(vfloat4*)(hb + 1024 + lane * 16);
                    float* dst = trajBase + (size_t)row * H_;
                    *(vfloat4*)(dst + lane * 4)       = v;
                    *(vfloat4*)(dst + 256 + lane * 4) = w;
                }
            }
            barrier_lds();
        }
    }

    // All waves: flush per-step outputs (os visible after the final barrier).
    float* outp = out + (size_t)b * T_;
    for (int idx = tid; idx < T_; idx += 192)
        outp[idx] = os[idx + 1];
}

extern "C" void kernel_launch(void* const* d_in, const int* in_sizes, int n_in,
                              void* d_out, int out_size, void* d_ws, size_t ws_size,
                              hipStream_t stream) {
    const float* input = (const float*)d_in[0];
    const float* noise = (const float*)d_in[1];
    const float* wi    = (const float*)d_in[2];
    const float* si    = (const float*)d_in[3];
    const float* m     = (const float*)d_in[4];
    const float* n     = (const float*)d_in[5];
    const float* wo    = (const float*)d_in[6];
    const float* so    = (const float*)d_in[7];
    const float* h0    = (const float*)d_in[8];
    float* out = (float*)d_out;

    hipLaunchKernelGGL(lowrank_rnn_kernel, dim3(B_), dim3(192), 0, stream,
                       input, noise, wi, si, m, n, wo, so, h0, out);
}

// Round 7
// 404.736 us; speedup vs baseline: 1.2304x; 1.2304x over previous
//
#include <hip/hip_runtime.h>
#include <stdint.h>

#define B_ 128
#define T_ 1000
#define H_ 512
#define PH 8          // steps per phase
#define NPHASE 125    // T_/PH

typedef float vfloat4 __attribute__((ext_vector_type(4)));

// DPP-based add of a lane-shifted copy. row_shr:N = 0x110|N, row_bcast:15/31 = 0x142/0x143.
template <int CTRL>
__device__ __forceinline__ float dpp_add(float x) {
    int moved = __builtin_amdgcn_update_dpp(0, __float_as_int(x), CTRL, 0xf, 0xf, true);
    return x + __int_as_float(moved);
}

// Wave64 sum of 3 values simultaneously (3-way ILP covers DPP latency). Valid in lane 63.
__device__ __forceinline__ void wave_reduce3(float& p0, float& p1, float& p2) {
    p0 = dpp_add<0x111>(p0); p1 = dpp_add<0x111>(p1); p2 = dpp_add<0x111>(p2);
    p0 = dpp_add<0x112>(p0); p1 = dpp_add<0x112>(p1); p2 = dpp_add<0x112>(p2);
    p0 = dpp_add<0x114>(p0); p1 = dpp_add<0x114>(p1); p2 = dpp_add<0x114>(p2);
    p0 = dpp_add<0x118>(p0); p1 = dpp_add<0x118>(p1); p2 = dpp_add<0x118>(p2);
    p0 = dpp_add<0x142>(p0); p1 = dpp_add<0x142>(p1); p2 = dpp_add<0x142>(p2);
    p0 = dpp_add<0x143>(p0); p1 = dpp_add<0x143>(p1); p2 = dpp_add<0x143>(p2);
}

// tanh(x) = 1 - 2/(e^{2x}+1) via hardware exp2 + rcp.
__device__ __forceinline__ float fast_tanh(float x) {
    float E = __builtin_amdgcn_exp2f(x * 2.885390081777927f);
    float r = __builtin_amdgcn_rcpf(E + 1.0f);
    return __builtin_fmaf(-2.0f, r, 1.0f);
}

// Async global->LDS DMA, 16B/lane. LDS dest = wave-uniform base + lane*16.
// Side-effecting: the scheduler can neither sink it nor turn it into VGPR pressure.
__device__ __forceinline__ void gl_lds16(const float* g, float* l) {
    __builtin_amdgcn_global_load_lds(
        (const __attribute__((address_space(1))) uint32_t*)g,
        (__attribute__((address_space(3))) uint32_t*)l, 16, 0, 0);
}

__global__ __launch_bounds__(64, 1) void lowrank_rnn_kernel(
    const float* __restrict__ input,   // (B,T,3)
    const float* __restrict__ noise,   // (B,T,H)
    const float* __restrict__ wi,      // (3,H)
    const float* __restrict__ si,      // (3,)
    const float* __restrict__ m,       // (H,2)
    const float* __restrict__ n,       // (H,2)
    const float* __restrict__ wo,      // (H,1)
    const float* __restrict__ so,      // (1,)
    const float* __restrict__ h0,      // (H,)
    float* __restrict__ out)           // [output (B,T,1) | traj (B,T+1,H)]
{
    const int b    = blockIdx.x;   // one batch element per 64-thread block (1 wave)
    const int lane = threadIdx.x;
    const int j0   = lane * 8;     // this lane owns hidden units j0..j0+7

    // z layout per row: [0,1KB) = z[8L..8L+4) at float offset 4L; [1KB,2KB) = z[8L+4..8L+8).
    // ds_read_b128 at lane*16B stride -> conflict-free.
    __shared__ __align__(16) float zbuf[3][PH][H_];   // 48 KB, 3 banks x 8 rows
    __shared__ float xs[T_ * 3];                      // 12 KB
    __shared__ float os[T_ + 1];                      //  4 KB

    // ---- stage x into LDS (coalesced vfloat4; older than all DMAs in vmcnt order) ----
    const float* xg = input + (size_t)b * T_ * 3;
    for (int idx = lane; idx < (T_ * 3) / 4; idx += 64)
        *(vfloat4*)&xs[idx * 4] = *(const vfloat4*)(xg + idx * 4);

    // ---- per-lane constants (ALPHA=0.2 folded into m, wi; so into wo) ----
    float h[8], n0[8], n1[8], m0S[8], m1S[8], wof[8], wS0[8], wS1[8], wS2[8];
    {
        const float so0 = so[0];
        const float* nb = n + 2 * j0;
        const float* mb = m + 2 * j0;
        #pragma unroll
        for (int q = 0; q < 4; ++q) {
            vfloat4 vn = *(const vfloat4*)(nb + 4 * q);
            n0[2*q] = vn.x; n1[2*q] = vn.y; n0[2*q+1] = vn.z; n1[2*q+1] = vn.w;
            vfloat4 vm = *(const vfloat4*)(mb + 4 * q);
            m0S[2*q] = 0.2f * vm.x;   m1S[2*q] = 0.2f * vm.y;
            m0S[2*q+1] = 0.2f * vm.z; m1S[2*q+1] = 0.2f * vm.w;
        }
        #pragma unroll
        for (int q = 0; q < 2; ++q) {
            vfloat4 vw = *(const vfloat4*)(wo + j0 + 4 * q);
            wof[4*q] = vw.x * so0; wof[4*q+1] = vw.y * so0;
            wof[4*q+2] = vw.z * so0; wof[4*q+3] = vw.w * so0;
            vfloat4 vh = *(const vfloat4*)(h0 + j0 + 4 * q);
            h[4*q] = vh.x; h[4*q+1] = vh.y; h[4*q+2] = vh.z; h[4*q+3] = vh.w;
        }
        #pragma unroll
        for (int i = 0; i < 3; ++i) {
            float s = 0.2f * si[i];
            float* dst = (i == 0) ? wS0 : (i == 1) ? wS1 : wS2;
            #pragma unroll
            for (int q = 0; q < 2; ++q) {
                vfloat4 vw = *(const vfloat4*)(wi + i * H_ + j0 + 4 * q);
                dst[4*q] = vw.x * s; dst[4*q+1] = vw.y * s;
                dst[4*q+2] = vw.z * s; dst[4*q+3] = vw.w * s;
            }
        }
    }

    float* trajBase = out + (size_t)B_ * T_ + (size_t)b * (T_ + 1) * H_;
    {   // trajectories[:,0,:] = h0
        vfloat4 lo = {h[0], h[1], h[2], h[3]};
        vfloat4 hi = {h[4], h[5], h[6], h[7]};
        *(vfloat4*)(trajBase + j0)     = lo;
        *(vfloat4*)(trajBase + j0 + 4) = hi;
    }

    const float* zb0 = noise + (size_t)b * T_ * H_ + j0;
    auto dma_row = [&](int row, int bank, int slot) {
        const float* g = zb0 + (size_t)row * H_;
        gl_lds16(g,     &zbuf[bank][slot][0]);
        gl_lds16(g + 4, &zbuf[bank][slot][256]);
    };

    // Prologue: banks 0,1 <- rows 0..15 (32 DMA ops in flight).
    for (int s = 0; s < PH; ++s) dma_row(s, 0, s);
    for (int s = 0; s < PH; ++s) dma_row(PH + s, 1, s);

    for (int ph = 0; ph < NPHASE; ++ph) {
        // Wait for bank(ph)'s 16 DMAs. Counted: leave younger ops in flight.
        //  ph=0: younger = DMA bank1 (16).  ph=1: + DMA bank2, stores(ph0) (32).
        //  ph>=2: stores(p-2) 16 + DMA(p+1) 16 + stores(p-1) 16 = 48 (worst case).
        if (ph == 0)      asm volatile("s_waitcnt vmcnt(16)" ::: "memory");
        else if (ph == 1) asm volatile("s_waitcnt vmcnt(32)" ::: "memory");
        else              asm volatile("s_waitcnt vmcnt(48)" ::: "memory");
        __builtin_amdgcn_sched_barrier(0);

        // Issue DMAs for phase ph+2 (clamped rows keep counts uniform at the tail).
        {
            const int rb = (ph + 2) * PH;
            const int bank2 = (ph + 2) % 3;
            #pragma unroll
            for (int s = 0; s < PH; ++s) {
                int row = rb + s; if (row > T_ - 1) row = T_ - 1;
                dma_row(row, bank2, s);
            }
        }
        __builtin_amdgcn_sched_barrier(0);

        const int bank = ph % 3;
        const int t0 = ph * PH;
        #pragma unroll
        for (int s = 0; s < PH; ++s) {
            const int t = t0 + s;
            char* zrow = (char*)&zbuf[bank][s][0];
            vfloat4 zl = *(vfloat4*)(zrow + lane * 16);          // z[j0..j0+4)
            vfloat4 zh = *(vfloat4*)(zrow + 1024 + lane * 16);   // z[j0+4..j0+8)
            float cx0 = xs[3*t], cx1 = xs[3*t+1], cx2 = xs[3*t+2]; // broadcast reads

            float r[8];
            #pragma unroll
            for (int k = 0; k < 8; ++k) r[k] = fast_tanh(h[k]);

            float p0 = r[0] * n0[0], p1 = r[0] * n1[0], p2 = r[0] * wof[0];
            #pragma unroll
            for (int k = 1; k < 8; ++k) {
                p0 = __builtin_fmaf(r[k], n0[k], p0);
                p1 = __builtin_fmaf(r[k], n1[k], p1);
                p2 = __builtin_fmaf(r[k], wof[k], p2);
            }
            wave_reduce3(p0, p1, p2);

            // Independent of the reduction: fills issue slots while DPP chain runs.
            float zz[8] = {zl.x, zl.y, zl.z, zl.w, zh.x, zh.y, zh.z, zh.w};
            float base[8];
            #pragma unroll
            for (int k = 0; k < 8; ++k) {
                float xw = __builtin_fmaf(cx0, wS0[k],
                           __builtin_fmaf(cx1, wS1[k], cx2 * wS2[k]));
                base[k] = __builtin_fmaf(h[k], 0.8f,
                          __builtin_fmaf(zz[k], 0.05f, xw));
            }

            float a0 = __int_as_float(__builtin_amdgcn_readlane(__float_as_int(p0), 63));
            float a1 = __int_as_float(__builtin_amdgcn_readlane(__float_as_int(p1), 63));
            if (lane == 63) os[t] = p2;   // out[t-1] = tanh(h_t)·wo_full

            #pragma unroll
            for (int k = 0; k < 8; ++k)
                h[k] = __builtin_fmaf(a0, m0S[k], __builtin_fmaf(a1, m1S[k], base[k]));

            // Plain stores: younger than any load we ever wait on -> never block.
            float* tr = trajBase + (size_t)(t + 1) * H_ + j0;
            vfloat4 lo = {h[0], h[1], h[2], h[3]};
            vfloat4 hi = {h[4], h[5], h[6], h[7]};
            *(vfloat4*)tr       = lo;
            *(vfloat4*)(tr + 4) = hi;
        }
    }

    // Final output: out[T-1] = tanh(h_T)·wo_full
    {
        float r[8];
        #pragma unroll
        for (int k = 0; k < 8; ++k) r[k] = fast_tanh(h[k]);
        float p2 = r[0] * wof[0];
        #pragma unroll
        for (int k = 1; k < 8; ++k) p2 = __builtin_fmaf(r[k], wof[k], p2);
        p2 = dpp_add<0x111>(p2); p2 = dpp_add<0x112>(p2);
        p2 = dpp_add<0x114>(p2); p2 = dpp_add<0x118>(p2);
        p2 = dpp_add<0x142>(p2); p2 = dpp_add<0x143>(p2);
        if (lane == 63) os[T_] = p2;
    }

    // Single wave: lgkmcnt orders the ds ops; no barrier needed.
    float* outp = out + (size_t)b * T_;
    for (int idx = lane; idx < T_; idx += 64)
        outp[idx] = os[idx + 1];
}

extern "C" void kernel_launch(void* const* d_in, const int* in_sizes, int n_in,
                              void* d_out, int out_size, void* d_ws, size_t ws_size,
                              hipStream_t stream) {
    const float* input = (const float*)d_in[0];
    const float* noise = (const float*)d_in[1];
    const float* wi    = (const float*)d_in[2];
    const float* si    = (const float*)d_in[3];
    const float* m     = (const float*)d_in[4];
    const float* n     = (const float*)d_in[5];
    const float* wo    = (const float*)d_in[6];
    const float* so    = (const float*)d_in[7];
    const float* h0    = (const float*)d_in[8];
    float* out = (float*)d_out;

    hipLaunchKernelGGL(lowrank_rnn_kernel, dim3(B_), dim3(64), 0, stream,
                       input, noise, wi, si, m, n, wo, so, h0, out);
}

// Round 8
// 290.304 us; speedup vs baseline: 1.7154x; 1.3942x over previous
//
#include <hip/hip_runtime.h>
#include <stdint.h>

#define B_ 128
#define T_ 1000
#define H_ 512
#define PH 8          // steps per phase
#define NPHASE 125    // T_/PH

typedef float vfloat4 __attribute__((ext_vector_type(4)));

// DPP-based add of a lane-shifted copy. row_shr:N = 0x110|N, row_bcast:15/31 = 0x142/0x143.
template <int CTRL>
__device__ __forceinline__ float dpp_add(float x) {
    int moved = __builtin_amdgcn_update_dpp(0, __float_as_int(x), CTRL, 0xf, 0xf, true);
    return x + __int_as_float(moved);
}

// Wave64 sum of 3 values simultaneously (3-way ILP covers DPP latency). Valid in lane 63.
__device__ __forceinline__ void wave_reduce3(float& p0, float& p1, float& p2) {
    p0 = dpp_add<0x111>(p0); p1 = dpp_add<0x111>(p1); p2 = dpp_add<0x111>(p2);
    p0 = dpp_add<0x112>(p0); p1 = dpp_add<0x112>(p1); p2 = dpp_add<0x112>(p2);
    p0 = dpp_add<0x114>(p0); p1 = dpp_add<0x114>(p1); p2 = dpp_add<0x114>(p2);
    p0 = dpp_add<0x118>(p0); p1 = dpp_add<0x118>(p1); p2 = dpp_add<0x118>(p2);
    p0 = dpp_add<0x142>(p0); p1 = dpp_add<0x142>(p1); p2 = dpp_add<0x142>(p2);
    p0 = dpp_add<0x143>(p0); p1 = dpp_add<0x143>(p1); p2 = dpp_add<0x143>(p2);
}

// tanh(x) = 1 - 2/(e^{2x}+1) via hardware exp2 + rcp.
__device__ __forceinline__ float fast_tanh(float x) {
    float E = __builtin_amdgcn_exp2f(x * 2.885390081777927f);
    float r = __builtin_amdgcn_rcpf(E + 1.0f);
    return __builtin_fmaf(-2.0f, r, 1.0f);
}

__global__ __launch_bounds__(128, 1) void lowrank_rnn_kernel(
    const float* __restrict__ input,   // (B,T,3)
    const float* __restrict__ noise,   // (B,T,H)
    const float* __restrict__ wi,      // (3,H)
    const float* __restrict__ si,      // (3,)
    const float* __restrict__ m,       // (H,2)
    const float* __restrict__ n,       // (H,2)
    const float* __restrict__ wo,      // (H,1)
    const float* __restrict__ so,      // (1,)
    const float* __restrict__ h0,      // (H,)
    float* __restrict__ out)           // [output (B,T,1) | traj (B,T+1,H)]
{
    const int b    = blockIdx.x;   // one batch element per block (2 waves)
    const int tid  = threadIdx.x;
    const int wid  = tid >> 6;     // 0 = consumer (serial chain), 1 = producer
    const int lane = tid & 63;
    const int j0   = lane * 8;     // hidden units j0..j0+7 owned by this lane

    // u ring: [half][row-in-phase][plane][lane] — 16B/lane stride, conflict-free
    // for both producer ds_write_b128 and consumer ds_read_b128.
    __shared__ __align__(16) vfloat4 ub[2][PH][2][64];   // 32 KB
    __shared__ float os[T_ + 1];                         //  4 KB
    __shared__ int   flags[2];                           // [0]=produced, [1]=consumed

    if (tid == 0) { flags[0] = 0; flags[1] = 0; }
    __syncthreads();   // one full barrier at start only
    volatile int* vprod = &flags[0];
    volatile int* vcons = &flags[1];

    if (wid == 1) {
        // ============ PRODUCER: z loads + u precompute. Infinite slack. ============
        float wS0[8], wS1[8], wS2[8];
        #pragma unroll
        for (int i = 0; i < 3; ++i) {
            float s = 0.2f * si[i];
            float* dst = (i == 0) ? wS0 : (i == 1) ? wS1 : wS2;
            #pragma unroll
            for (int q = 0; q < 2; ++q) {
                vfloat4 vw = *(const vfloat4*)(wi + i * H_ + j0 + 4 * q);
                dst[4*q] = vw.x * s; dst[4*q+1] = vw.y * s;
                dst[4*q+2] = vw.z * s; dst[4*q+3] = vw.w * s;
            }
        }
        const float* zb = noise + (size_t)b * T_ * H_ + j0;
        const float* xb = input + (size_t)b * T_ * 3;   // uniform -> SMEM

        for (int p = 0; p < NPHASE; ++p) {
            if (p >= 2) {                       // ring holds 2 phases
                while (*vcons < p - 1) {}
                asm volatile("" ::: "memory");
            }
            const int half = p & 1;
            #pragma unroll
            for (int s = 0; s < PH; ++s) {
                const int t = p * PH + s;
                vfloat4 zl = *(const vfloat4*)(zb + (size_t)t * H_);
                vfloat4 zh = *(const vfloat4*)(zb + (size_t)t * H_ + 4);
                float x0 = xb[3*t], x1 = xb[3*t+1], x2 = xb[3*t+2];
                float zz[8] = {zl.x, zl.y, zl.z, zl.w, zh.x, zh.y, zh.z, zh.w};
                float u[8];
                #pragma unroll
                for (int k = 0; k < 8; ++k) {
                    float xw = __builtin_fmaf(x0, wS0[k],
                               __builtin_fmaf(x1, wS1[k], x2 * wS2[k]));
                    u[k] = __builtin_fmaf(zz[k], 0.05f, xw);
                }
                vfloat4 ulo = {u[0], u[1], u[2], u[3]};
                vfloat4 uhi = {u[4], u[5], u[6], u[7]};
                ub[half][s][0][lane] = ulo;
                ub[half][s][1][lane] = uhi;
            }
            asm volatile("s_waitcnt lgkmcnt(0)" ::: "memory");  // u-writes done
            if (lane == 0) *vprod = p + 1;
        }
    } else {
        // ============ CONSUMER: the serial chain. Zero VMEM loads in loop. ============
        float h[8], n0[8], n1[8], m0S[8], m1S[8], wof[8];
        {
            const float so0 = so[0];
            const float* nb = n + 2 * j0;
            const float* mb = m + 2 * j0;
            #pragma unroll
            for (int q = 0; q < 4; ++q) {
                vfloat4 vn = *(const vfloat4*)(nb + 4 * q);
                n0[2*q] = vn.x; n1[2*q] = vn.y; n0[2*q+1] = vn.z; n1[2*q+1] = vn.w;
                vfloat4 vm = *(const vfloat4*)(mb + 4 * q);
                m0S[2*q] = 0.2f * vm.x;   m1S[2*q] = 0.2f * vm.y;
                m0S[2*q+1] = 0.2f * vm.z; m1S[2*q+1] = 0.2f * vm.w;
            }
            #pragma unroll
            for (int q = 0; q < 2; ++q) {
                vfloat4 vw = *(const vfloat4*)(wo + j0 + 4 * q);
                wof[4*q] = vw.x * so0; wof[4*q+1] = vw.y * so0;
                wof[4*q+2] = vw.z * so0; wof[4*q+3] = vw.w * so0;
                vfloat4 vh = *(const vfloat4*)(h0 + j0 + 4 * q);
                h[4*q] = vh.x; h[4*q+1] = vh.y; h[4*q+2] = vh.z; h[4*q+3] = vh.w;
            }
        }
        float* trajBase = out + (size_t)B_ * T_ + (size_t)b * (T_ + 1) * H_;
        {   // trajectories[:,0,:] = h0
            vfloat4 lo = {h[0], h[1], h[2], h[3]};
            vfloat4 hi = {h[4], h[5], h[6], h[7]};
            *(vfloat4*)(trajBase + j0)     = lo;
            *(vfloat4*)(trajBase + j0 + 4) = hi;
        }

        for (int p = 0; p < NPHASE; ++p) {
            while (*vprod < p + 1) {}        // u for this phase ready
            asm volatile("" ::: "memory");   // no hoisting of ds_reads above spin
            const int half = p & 1;
            #pragma unroll
            for (int s = 0; s < PH; ++s) {
                const int t = p * PH + s;
                vfloat4 ulo = ub[half][s][0][lane];
                vfloat4 uhi = ub[half][s][1][lane];

                float r[8];
                #pragma unroll
                for (int k = 0; k < 8; ++k) r[k] = fast_tanh(h[k]);

                float p0 = r[0] * n0[0], p1 = r[0] * n1[0], p2 = r[0] * wof[0];
                #pragma unroll
                for (int k = 1; k < 8; ++k) {
                    p0 = __builtin_fmaf(r[k], n0[k], p0);
                    p1 = __builtin_fmaf(r[k], n1[k], p1);
                    p2 = __builtin_fmaf(r[k], wof[k], p2);
                }
                wave_reduce3(p0, p1, p2);

                float uu[8] = {ulo.x, ulo.y, ulo.z, ulo.w, uhi.x, uhi.y, uhi.z, uhi.w};
                float base[8];
                #pragma unroll
                for (int k = 0; k < 8; ++k)
                    base[k] = __builtin_fmaf(h[k], 0.8f, uu[k]);

                float a0 = __int_as_float(__builtin_amdgcn_readlane(__float_as_int(p0), 63));
                float a1 = __int_as_float(__builtin_amdgcn_readlane(__float_as_int(p1), 63));
                if (lane == 63) os[t] = p2;   // out[t-1] = tanh(h_t)·wo_full

                #pragma unroll
                for (int k = 0; k < 8; ++k)
                    h[k] = __builtin_fmaf(a0, m0S[k], __builtin_fmaf(a1, m1S[k], base[k]));

                // Fire-and-forget: consumer never executes a vmcnt wait.
                float* tr = trajBase + (size_t)(t + 1) * H_ + j0;
                vfloat4 lo = {h[0], h[1], h[2], h[3]};
                vfloat4 hi = {h[4], h[5], h[6], h[7]};
                *(vfloat4*)tr       = lo;
                *(vfloat4*)(tr + 4) = hi;
            }
            asm volatile("s_waitcnt lgkmcnt(0)" ::: "memory");  // u-reads done
            if (lane == 0) *vcons = p + 1;
        }

        // Final output: out[T-1] = tanh(h_T)·wo_full
        {
            float r[8];
            #pragma unroll
            for (int k = 0; k < 8; ++k) r[k] = fast_tanh(h[k]);
            float p2 = r[0] * wof[0];
            #pragma unroll
            for (int k = 1; k < 8; ++k) p2 = __builtin_fmaf(r[k], wof[k], p2);
            p2 = dpp_add<0x111>(p2); p2 = dpp_add<0x112>(p2);
            p2 = dpp_add<0x114>(p2); p2 = dpp_add<0x118>(p2);
            p2 = dpp_add<0x142>(p2); p2 = dpp_add<0x143>(p2);
            if (lane == 63) os[T_] = p2;
        }
        // Flush per-step outputs (single wave: lgkmcnt orders the ds ops).
        float* outp = out + (size_t)b * T_;
        for (int idx = lane; idx < T_; idx += 64)
            outp[idx] = os[idx + 1];
    }
}

extern "C" void kernel_launch(void* const* d_in, const int* in_sizes, int n_in,
                              void* d_out, int out_size, void* d_ws, size_t ws_size,
                              hipStream_t stream) {
    const float* input = (const float*)d_in[0];
    const float* noise = (const float*)d_in[1];
    const float* wi    = (const float*)d_in[2];
    const float* si    = (const float*)d_in[3];
    const float* m     = (const float*)d_in[4];
    const float* n     = (const float*)d_in[5];
    const float* wo    = (const float*)d_in[6];
    const float* so    = (const float*)d_in[7];
    const float* h0    = (const float*)d_in[8];
    float* out = (float*)d_out;

    hipLaunchKernelGGL(lowrank_rnn_kernel, dim3(B_), dim3(128), 0, stream,
                       input, noise, wi, si, m, n, wo, so, h0, out);
}